// Round 3
// baseline (163.229 us; speedup 1.0000x reference)
//
#include <hip/hip_runtime.h>
#include <hip/hip_bf16.h>
#include <cstdint>
#include <cstddef>

#define BATCH 8192
#define IDIM  768
#define JDIM  768
#define GRID  5
#define KDIM  (IDIM * GRID)   // 3840

// ---------------- helpers ----------------

__device__ __forceinline__ unsigned short f2bf(float f) {
    // round-to-nearest-even fp32 -> bf16 bits (inputs here are finite)
    unsigned int u = __float_as_uint(f);
    u += 0x7fffu + ((u >> 16) & 1u);
    return (unsigned short)(u >> 16);
}

typedef __bf16 bf16x8 __attribute__((ext_vector_type(8)));
typedef float  f32x4  __attribute__((ext_vector_type(4)));
typedef unsigned short ushortx4 __attribute__((ext_vector_type(4)));

__device__ __forceinline__ void async_copy16(const void* gsrc, void* ldsdst) {
    __builtin_amdgcn_global_load_lds(
        (const __attribute__((address_space(1))) unsigned int*)gsrc,
        (__attribute__((address_space(3))) unsigned int*)ldsdst,
        16, 0, 0);
}

// ---------------- precompute: Wt + bias (fused, LDS transpose) ----------------
// Wt[j][g*768+i] = bf16(coeffs[i,j,g]*scale[i,j]);  bias[j] += sum_i shift[i,j]
// Tile: 32 i x 64 j. Reads coalesced over j; writes coalesced over i (ushort4).

#define WT_I 32
#define WT_J 64

__global__ __launch_bounds__(256)
void wt_bias_kernel(const float* __restrict__ coeffs,
                    const float* __restrict__ scale,
                    const float* __restrict__ shift,
                    unsigned short* __restrict__ Wt,
                    float* __restrict__ bias) {
    __shared__ __align__(16) unsigned short tile[GRID][WT_J][WT_I + 4]; // pad->36 (72B rows, 8B aligned)
    __shared__ float red[4][WT_J];
    const int t  = threadIdx.x;
    const int i0 = (blockIdx.x / (JDIM / WT_J)) * WT_I;
    const int j0 = (blockIdx.x % (JDIM / WT_J)) * WT_J;
    const int jj = t & 63;

    float ssum = 0.f;
#pragma unroll
    for (int it = 0; it < (WT_I * WT_J) / 256; ++it) {          // 8 iters
        const int ii = it * 4 + (t >> 6);
        const int i = i0 + ii, j = j0 + jj;
        const float* cp = &coeffs[((size_t)i * JDIM + j) * GRID];
        const float  sc = scale[(size_t)i * JDIM + j];
        ssum += shift[(size_t)i * JDIM + j];
#pragma unroll
        for (int g = 0; g < GRID; ++g)
            tile[g][jj][ii] = f2bf(cp[g] * sc);
    }
    red[t >> 6][jj] = ssum;
    __syncthreads();
    if (t < WT_J)
        atomicAdd(&bias[j0 + t], red[0][t] + red[1][t] + red[2][t] + red[3][t]);

    // write out: 64j * 5g * 8 ushort4 = 2560 stores / 256 threads = 10 iters
#pragma unroll
    for (int it = 0; it < (WT_J * GRID * (WT_I / 4)) / 256; ++it) {
        const int p  = it * 256 + t;
        const int iq = p & 7;
        const int q  = p >> 3;
        const int g  = q % GRID;
        const int j  = q / GRID;
        ushortx4 v = *(const ushortx4*)&tile[g][j][iq * 4];
        *(ushortx4*)&Wt[(size_t)(j0 + j) * KDIM + g * IDIM + i0 + iq * 4] = v;
    }
}

// ---------------- precompute: basis ----------------
// Abas[b][g*768+i] = bf16(exp(-5*(tanh(x[b,i]) - grid[g])^2)); 4 i's per thread.

__global__ __launch_bounds__(256)
void basis_kernel(const float* __restrict__ x, unsigned short* __restrict__ Abas) {
    const int idx = blockIdx.x * 256 + threadIdx.x;           // over BATCH*192, exact
    const int b  = idx / (IDIM / 4);
    const int i4 = (idx - b * (IDIM / 4)) * 4;
    const float4 xv = *(const float4*)&x[(size_t)b * IDIM + i4];
    const float xs[4] = {xv.x, xv.y, xv.z, xv.w};
    float tv[4];
#pragma unroll
    for (int u = 0; u < 4; ++u) {
        // tanh(x) = 1 - 2/(e^{2x}+1); saturates correctly at +-inf
        const float e = __expf(2.f * xs[u]);
        tv[u] = 1.f - 2.f / (e + 1.f);
    }
#pragma unroll
    for (int g = 0; g < GRID; ++g) {
        const float gv = -1.f + 0.5f * (float)g;
        ushortx4 o;
#pragma unroll
        for (int u = 0; u < 4; ++u) {
            const float d = tv[u] - gv;
            o[u] = f2bf(__expf(-5.f * d * d));
        }
        *(ushortx4*)&Abas[(size_t)b * KDIM + g * IDIM + i4] = o;
    }
}

// ---------------- MFMA GEMM ----------------
// C[8192,768] = Abas @ Wt^T + bias.  BM=128, BN=96, BK=64.
// Grid = dim3(64, 8): linear id = n*64 + m, so XCD = id%8 = m%8 — all 8
// N-blocks of one M-panel share an XCD -> A-panel fetched to that L2 once,
// reused 8x (A L2-fill traffic 503 MB -> 63 MB).  [T1 mechanism]
// Double-buffered LDS, 2-phase pipeline: stage(t+1) issued BEFORE compute(t),
// single vmcnt(0)+barrier per tile AFTER compute -> HBM/L2 latency hides
// under the 24 MFMA of the current tile.  [T3 minimum-2-phase recipe]
// XOR k-chunk swizzle so ds_read_b128 fragment reads spread over all 32 banks.

#define BM 128
#define BN 96
#define BK 64

__global__ __launch_bounds__(256, 2)
void kan_gemm(const unsigned short* __restrict__ Abas,  // [BATCH][KDIM]
              const unsigned short* __restrict__ Wt,    // [JDIM][KDIM]
              const float* __restrict__ bias,           // [JDIM]
              float* __restrict__ out) {                // [BATCH][JDIM]
    __shared__ unsigned short As[2][BM * BK];  // 2 x 16 KB, [m][k] XOR-swizzled in 8-elem chunks
    __shared__ unsigned short Bs[2][BN * BK];  // 2 x 12 KB

    const int t    = threadIdx.x;
    const int lane = t & 63;
    const int wave = t >> 6;
    const int m0 = blockIdx.x * BM;            // grid transposed: x = M-panel
    const int n0 = blockIdx.y * BN;            //                  y = N-panel
    const int wm = (wave >> 1) * 64;   // 0 / 64
    const int wn = (wave & 1) * 48;    // 0 / 48

    f32x4 acc[4][3] = {};

    // staging: thread t owns LDS slot (row=t>>3, chunk=t&7) = bytes t*16.
    // source chunk is XOR-swizzled: LDS[r][c] holds global chunk c^(r&7).
    const int lrow = t >> 3;
    const int lc   = t & 7;
    const int cg   = lc ^ (lrow & 7);
    const int ldsoff = lrow * BK + lc * 8;                 // elements
    const size_t abase = (size_t)(m0 + lrow) * KDIM + cg * 8;
    const size_t bbase = (size_t)(n0 + lrow) * KDIM + cg * 8;

    // ---- prologue: stage tile kt=0 into buffer 0 ----
#pragma unroll
    for (int s = 0; s < 4; ++s)
        async_copy16(&Abas[abase + (size_t)(32 * s) * KDIM], &As[0][ldsoff + 32 * s * BK]);
#pragma unroll
    for (int s = 0; s < 3; ++s)
        async_copy16(&Wt[bbase + (size_t)(32 * s) * KDIM], &Bs[0][ldsoff + 32 * s * BK]);
    asm volatile("s_waitcnt vmcnt(0)" ::: "memory");
    __syncthreads();

    int cur = 0;
    for (int kt = 0; kt < KDIM; kt += BK) {
        const int nxt = cur ^ 1;
        // ---- issue next tile's loads first (overlap with compute below) ----
        if (kt + BK < KDIM) {
#pragma unroll
            for (int s = 0; s < 4; ++s)
                async_copy16(&Abas[abase + (size_t)(32 * s) * KDIM + kt + BK],
                             &As[nxt][ldsoff + 32 * s * BK]);
#pragma unroll
            for (int s = 0; s < 3; ++s)
                async_copy16(&Wt[bbase + (size_t)(32 * s) * KDIM + kt + BK],
                             &Bs[nxt][ldsoff + 32 * s * BK]);
        }

        // ---- compute current tile ----
#pragma unroll
        for (int ks = 0; ks < 2; ++ks) {
            // logical chunk = ks*4 + (lane>>4); row&7 == lane&7 for all fragment rows
            const int pc = ((ks * 4) + (lane >> 4)) ^ (lane & 7);
            bf16x8 af[4], bfr[3];
#pragma unroll
            for (int f = 0; f < 4; ++f)
                af[f]  = *(const bf16x8*)&As[cur][(wm + f * 16 + (lane & 15)) * BK + pc * 8];
#pragma unroll
            for (int f = 0; f < 3; ++f)
                bfr[f] = *(const bf16x8*)&Bs[cur][(wn + f * 16 + (lane & 15)) * BK + pc * 8];
#pragma unroll
            for (int fm = 0; fm < 4; ++fm)
#pragma unroll
                for (int fn = 0; fn < 3; ++fn)
                    acc[fm][fn] = __builtin_amdgcn_mfma_f32_16x16x32_bf16(
                        af[fm], bfr[fn], acc[fm][fn], 0, 0, 0);
        }

        // ---- publish prefetched tile; release current buffer ----
        asm volatile("s_waitcnt vmcnt(0)" ::: "memory");
        __syncthreads();
        cur = nxt;
    }

    // epilogue: D mapping col=lane&15, row=(lane>>4)*4+reg  [measured m89/m91]
    const int col   = lane & 15;
    const int rbase = (lane >> 4) * 4;
#pragma unroll
    for (int fm = 0; fm < 4; ++fm) {
#pragma unroll
        for (int fn = 0; fn < 3; ++fn) {
            const int j  = n0 + wn + fn * 16 + col;
            const float bj = bias[j];
#pragma unroll
            for (int r = 0; r < 4; ++r) {
                const int row = m0 + wm + fm * 16 + rbase + r;
                out[(size_t)row * JDIM + j] = acc[fm][fn][r] + bj;
            }
        }
    }
}

// ---------------- fallback (ws too small): slow but correct ----------------

__global__ __launch_bounds__(256)
void fallback_kernel(const float* __restrict__ x,
                     const float* __restrict__ coeffs,
                     const float* __restrict__ scale,
                     const float* __restrict__ shift,
                     float* __restrict__ out) {
    __shared__ float bas[KDIM];
    const int b = blockIdx.x;
    const int t = threadIdx.x;
    for (int i = t; i < IDIM; i += 256) {
        float tv = tanhf(x[(size_t)b * IDIM + i]);
#pragma unroll
        for (int g = 0; g < GRID; ++g) {
            float d = tv - (-1.0f + 0.5f * (float)g);
            bas[g * IDIM + i] = __expf(-5.0f * d * d);
        }
    }
    __syncthreads();
#pragma unroll
    for (int jj = 0; jj < 3; ++jj) {
        const int j = t + jj * 256;
        float acc = 0.f;
        for (int i = 0; i < IDIM; ++i) {
            const float sc = scale[(size_t)i * JDIM + j];
            const float* cp = &coeffs[((size_t)i * JDIM + j) * GRID];
            float s5 = 0.f;
#pragma unroll
            for (int g = 0; g < GRID; ++g) s5 += bas[g * IDIM + i] * cp[g];
            acc += s5 * sc + shift[(size_t)i * JDIM + j];
        }
        out[(size_t)b * JDIM + j] = acc;
    }
}

// ---------------- launch ----------------

extern "C" void kernel_launch(void* const* d_in, const int* in_sizes, int n_in,
                              void* d_out, int out_size, void* d_ws, size_t ws_size,
                              hipStream_t stream) {
    const float* x      = (const float*)d_in[0];
    const float* coeffs = (const float*)d_in[1];
    const float* scale  = (const float*)d_in[2];
    const float* shift  = (const float*)d_in[3];
    float* out = (float*)d_out;

    const size_t wt_bytes   = (size_t)JDIM * KDIM * sizeof(unsigned short); // 5,898,240
    const size_t bias_off   = wt_bytes;
    const size_t bias_bytes = (size_t)JDIM * sizeof(float);
    const size_t bas_off    = bias_off + bias_bytes;
    const size_t bas_bytes  = (size_t)BATCH * KDIM * sizeof(unsigned short);
    const size_t need       = bas_off + bas_bytes;                          // ~68.8 MB

    if (ws_size >= need) {
        unsigned short* Wt   = (unsigned short*)d_ws;
        float*          bias = (float*)((char*)d_ws + bias_off);
        unsigned short* Abas = (unsigned short*)((char*)d_ws + bas_off);

        hipMemsetAsync(bias, 0, bias_bytes, stream);
        wt_bias_kernel<<<(IDIM / WT_I) * (JDIM / WT_J), 256, 0, stream>>>(coeffs, scale, shift, Wt, bias);
        basis_kernel<<<(BATCH * (IDIM / 4)) / 256, 256, 0, stream>>>(x, Abas);
        kan_gemm<<<dim3(BATCH / BM, JDIM / BN), 256, 0, stream>>>(Abas, Wt, bias, out);
    } else {
        fallback_kernel<<<BATCH, 256, 0, stream>>>(x, coeffs, scale, shift, out);
    }
}

// Round 8
// 157.279 us; speedup vs baseline: 1.0378x; 1.0378x over previous
//
#include <hip/hip_runtime.h>
#include <hip/hip_bf16.h>
#include <cstdint>
#include <cstddef>

#define BATCH 8192
#define IDIM  768
#define JDIM  768
#define GRID  5
#define KDIM  (IDIM * GRID)   // 3840

// ---------------- helpers ----------------

__device__ __forceinline__ unsigned short f2bf(float f) {
    // round-to-nearest-even fp32 -> bf16 bits (inputs here are finite)
    unsigned int u = __float_as_uint(f);
    u += 0x7fffu + ((u >> 16) & 1u);
    return (unsigned short)(u >> 16);
}

typedef __bf16 bf16x8 __attribute__((ext_vector_type(8)));
typedef float  f32x4  __attribute__((ext_vector_type(4)));
typedef unsigned short ushortx4 __attribute__((ext_vector_type(4)));

__device__ __forceinline__ void async_copy16(const void* gsrc, void* ldsdst) {
    __builtin_amdgcn_global_load_lds(
        (const __attribute__((address_space(1))) unsigned int*)gsrc,
        (__attribute__((address_space(3))) unsigned int*)ldsdst,
        16, 0, 0);
}

// ---------------- precompute: Wt + bias (fused, LDS transpose) ----------------
// Wt[j][g*768+i] = bf16(coeffs[i,j,g]*scale[i,j]);  bias[j] += sum_i shift[i,j]

#define WT_I 32
#define WT_J 64

__global__ __launch_bounds__(256)
void wt_bias_kernel(const float* __restrict__ coeffs,
                    const float* __restrict__ scale,
                    const float* __restrict__ shift,
                    unsigned short* __restrict__ Wt,
                    float* __restrict__ bias) {
    __shared__ __align__(16) unsigned short tile[GRID][WT_J][WT_I + 4]; // pad->36 (72B rows, 8B aligned)
    __shared__ float red[4][WT_J];
    const int t  = threadIdx.x;
    const int i0 = (blockIdx.x / (JDIM / WT_J)) * WT_I;
    const int j0 = (blockIdx.x % (JDIM / WT_J)) * WT_J;
    const int jj = t & 63;

    float ssum = 0.f;
#pragma unroll
    for (int it = 0; it < (WT_I * WT_J) / 256; ++it) {          // 8 iters
        const int ii = it * 4 + (t >> 6);
        const int i = i0 + ii, j = j0 + jj;
        const float* cp = &coeffs[((size_t)i * JDIM + j) * GRID];
        const float  sc = scale[(size_t)i * JDIM + j];
        ssum += shift[(size_t)i * JDIM + j];
#pragma unroll
        for (int g = 0; g < GRID; ++g)
            tile[g][jj][ii] = f2bf(cp[g] * sc);
    }
    red[t >> 6][jj] = ssum;
    __syncthreads();
    if (t < WT_J)
        atomicAdd(&bias[j0 + t], red[0][t] + red[1][t] + red[2][t] + red[3][t]);

    // write out: 64j * 5g * 8 ushort4 = 2560 stores / 256 threads = 10 iters
#pragma unroll
    for (int it = 0; it < (WT_J * GRID * (WT_I / 4)) / 256; ++it) {
        const int p  = it * 256 + t;
        const int iq = p & 7;
        const int q  = p >> 3;
        const int g  = q % GRID;
        const int j  = q / GRID;
        ushortx4 v = *(const ushortx4*)&tile[g][j][iq * 4];
        *(ushortx4*)&Wt[(size_t)(j0 + j) * KDIM + g * IDIM + i0 + iq * 4] = v;
    }
}

// ---------------- precompute: basis ----------------

__global__ __launch_bounds__(256)
void basis_kernel(const float* __restrict__ x, unsigned short* __restrict__ Abas) {
    const int idx = blockIdx.x * 256 + threadIdx.x;           // over BATCH*192, exact
    const int b  = idx / (IDIM / 4);
    const int i4 = (idx - b * (IDIM / 4)) * 4;
    const float4 xv = *(const float4*)&x[(size_t)b * IDIM + i4];
    const float xs[4] = {xv.x, xv.y, xv.z, xv.w};
    float tv[4];
#pragma unroll
    for (int u = 0; u < 4; ++u) {
        // tanh(x) = 1 - 2/(e^{2x}+1); saturates correctly at +-inf
        const float e = __expf(2.f * xs[u]);
        tv[u] = 1.f - 2.f / (e + 1.f);
    }
#pragma unroll
    for (int g = 0; g < GRID; ++g) {
        const float gv = -1.f + 0.5f * (float)g;
        ushortx4 o;
#pragma unroll
        for (int u = 0; u < 4; ++u) {
            const float d = tv[u] - gv;
            o[u] = f2bf(__expf(-5.f * d * d));
        }
        *(ushortx4*)&Abas[(size_t)b * KDIM + g * IDIM + i4] = o;
    }
}

// ---------------- MFMA GEMM ----------------
// C[8192,768] = Abas @ Wt^T + bias.  BM=128, BN=96, BK=64.
// Grid = dim3(64, 8): XCD = id%8 = m%8 -> A-panel L2/L3 time-reuse (verified
// r3: FETCH 53.8 MB ~= one Abas pass).
// 3-deep A / 2-deep B LDS pipeline with COUNTED vmcnt(7) + raw s_barrier
// (no vmcnt(0) in main loop — T4).  A(t) issued 2 iters ahead covers HBM
// latency; B(t) 1 iter ahead covers L2.
// r5 fix: buffer rotation.  A(t) lives in buf t%3, so iteration tt computes
// from ac=tt%3 and stages into a2=(tt+2)%3 — BOTH advance +1 mod 3 per iter
// (the r4 code did ac=a2, skewing compute to A(tt+1) vs B(tt): wrong result).

#define BM 128
#define BN 96
#define BK 64
#define KT (KDIM / BK)   // 60

__global__ __launch_bounds__(256, 2)
void kan_gemm(const unsigned short* __restrict__ Abas,  // [BATCH][KDIM]
              const unsigned short* __restrict__ Wt,    // [JDIM][KDIM]
              const float* __restrict__ bias,           // [JDIM]
              float* __restrict__ out) {                // [BATCH][JDIM]
    __shared__ unsigned short As[3][BM * BK];  // 3 x 16 KB (A: HBM-latency, 2-tile lookahead)
    __shared__ unsigned short Bs[2][BN * BK];  // 2 x 12 KB (B: L2-resident, 1-tile lookahead)
    // 72 KB/block -> exactly 2 blocks/CU (144/160 KB)

    const int t    = threadIdx.x;
    const int lane = t & 63;
    const int wave = t >> 6;
    const int m0 = blockIdx.x * BM;            // grid transposed: x = M-panel
    const int n0 = blockIdx.y * BN;            //                  y = N-panel
    const int wm = (wave >> 1) * 64;   // 0 / 64
    const int wn = (wave & 1) * 48;    // 0 / 48

    f32x4 acc[4][3] = {};

    // staging: thread t owns LDS slot (row=t>>3, chunk=t&7) = bytes t*16.
    // source chunk is XOR-swizzled: LDS[r][c] holds global chunk c^(r&7).
    const int lrow = t >> 3;
    const int lc   = t & 7;
    const int cg   = lc ^ (lrow & 7);
    const int ldsoff = lrow * BK + lc * 8;                 // elements
    const size_t abase = (size_t)(m0 + lrow) * KDIM + cg * 8;
    const size_t bbase = (size_t)(n0 + lrow) * KDIM + cg * 8;

    // A tile: 128 rows = 4 sweeps of 32 rows; 4 loads/thread.
    auto stage_a = [&](int buf, int kt_el) {
#pragma unroll
        for (int s = 0; s < 4; ++s)
            async_copy16(&Abas[abase + (size_t)(32 * s) * KDIM + kt_el],
                         &As[buf][ldsoff + 32 * s * BK]);
    };
    // B tile: 96 rows = 3 sweeps; 3 loads/thread.
    auto stage_b = [&](int buf, int kt_el) {
#pragma unroll
        for (int s = 0; s < 3; ++s)
            async_copy16(&Wt[bbase + (size_t)(32 * s) * KDIM + kt_el],
                         &Bs[buf][ldsoff + 32 * s * BK]);
    };

    auto compute_tile = [&](int ab, int bb) {
#pragma unroll
        for (int ks = 0; ks < 2; ++ks) {
            // logical chunk = ks*4 + (lane>>4); row&7 == lane&7 for all fragment rows
            const int pc = ((ks * 4) + (lane >> 4)) ^ (lane & 7);
            bf16x8 af[4], bfr[3];
#pragma unroll
            for (int f = 0; f < 4; ++f)
                af[f]  = *(const bf16x8*)&As[ab][(wm + f * 16 + (lane & 15)) * BK + pc * 8];
#pragma unroll
            for (int f = 0; f < 3; ++f)
                bfr[f] = *(const bf16x8*)&Bs[bb][(wn + f * 16 + (lane & 15)) * BK + pc * 8];
#pragma unroll
            for (int fm = 0; fm < 4; ++fm)
#pragma unroll
                for (int fn = 0; fn < 3; ++fn)
                    acc[fm][fn] = __builtin_amdgcn_mfma_f32_16x16x32_bf16(
                        af[fm], bfr[fn], acc[fm][fn], 0, 0, 0);
        }
    };

    // ---- prologue: A(0), A(1), B(0) in flight ----
    stage_a(0, 0);
    stage_a(1, BK);
    stage_b(0, 0);

    // A(t) -> buf t%3.  ac = tt%3 (compute), a2 = (tt+2)%3 (stage target).
    int ac = 0, a2 = 2;
    // ---- main loop tt = 0..KT-3: steady state, counted vmcnt(7) ----
    for (int tt = 0; tt < KT - 2; ++tt) {
        stage_a(a2, (tt + 2) * BK);           // A(tt+2) into buf (tt+2)%3 = (tt-1)%3, freed at end of tt-1
        stage_b((tt + 1) & 1, (tt + 1) * BK); // B(tt+1)
        // wait until only A(tt+2)[4] + B(tt+1)[3] = 7 remain -> A(tt),B(tt) landed
        asm volatile("s_waitcnt vmcnt(7)" ::: "memory");
        __builtin_amdgcn_s_barrier();          // all waves' portions of tile tt are in LDS
        __builtin_amdgcn_sched_barrier(0);     // don't hoist ds_reads above the wait/barrier
        compute_tile(ac, tt & 1);
        __builtin_amdgcn_s_barrier();          // tile-tt buffers free for overwrite
        ac = (ac == 2) ? 0 : ac + 1;           // +1 mod 3 (r5 fix)
        a2 = (a2 == 2) ? 0 : a2 + 1;           // +1 mod 3
    }
    // ---- tt = KT-2: only B(KT-1) left to stage ----
    {
        const int tt = KT - 2;                 // ac == (KT-2)%3 == 1
        stage_b((tt + 1) & 1, (tt + 1) * BK);
        asm volatile("s_waitcnt vmcnt(3)" ::: "memory"); // leave B(KT-1)
        __builtin_amdgcn_s_barrier();
        __builtin_amdgcn_sched_barrier(0);
        compute_tile(ac, tt & 1);
        __builtin_amdgcn_s_barrier();
        ac = (ac == 2) ? 0 : ac + 1;           // -> (KT-1)%3 == 2
    }
    // ---- tt = KT-1: drain ----
    {
        const int tt = KT - 1;
        asm volatile("s_waitcnt vmcnt(0)" ::: "memory");
        __builtin_amdgcn_s_barrier();
        __builtin_amdgcn_sched_barrier(0);
        compute_tile(ac, tt & 1);
    }

    // epilogue: D mapping col=lane&15, row=(lane>>4)*4+reg  [measured m89/m91]
    const int col   = lane & 15;
    const int rbase = (lane >> 4) * 4;
#pragma unroll
    for (int fm = 0; fm < 4; ++fm) {
#pragma unroll
        for (int fn = 0; fn < 3; ++fn) {
            const int j  = n0 + wn + fn * 16 + col;
            const float bj = bias[j];
#pragma unroll
            for (int r = 0; r < 4; ++r) {
                const int row = m0 + wm + fm * 16 + rbase + r;
                out[(size_t)row * JDIM + j] = acc[fm][fn][r] + bj;
            }
        }
    }
}

// ---------------- fallback (ws too small): slow but correct ----------------

__global__ __launch_bounds__(256)
void fallback_kernel(const float* __restrict__ x,
                     const float* __restrict__ coeffs,
                     const float* __restrict__ scale,
                     const float* __restrict__ shift,
                     float* __restrict__ out) {
    __shared__ float bas[KDIM];
    const int b = blockIdx.x;
    const int t = threadIdx.x;
    for (int i = t; i < IDIM; i += 256) {
        float tv = tanhf(x[(size_t)b * IDIM + i]);
#pragma unroll
        for (int g = 0; g < GRID; ++g) {
            float d = tv - (-1.0f + 0.5f * (float)g);
            bas[g * IDIM + i] = __expf(-5.0f * d * d);
        }
    }
    __syncthreads();
#pragma unroll
    for (int jj = 0; jj < 3; ++jj) {
        const int j = t + jj * 256;
        float acc = 0.f;
        for (int i = 0; i < IDIM; ++i) {
            const float sc = scale[(size_t)i * JDIM + j];
            const float* cp = &coeffs[((size_t)i * JDIM + j) * GRID];
            float s5 = 0.f;
#pragma unroll
            for (int g = 0; g < GRID; ++g) s5 += bas[g * IDIM + i] * cp[g];
            acc += s5 * sc + shift[(size_t)i * JDIM + j];
        }
        out[(size_t)b * JDIM + j] = acc;
    }
}

// ---------------- launch ----------------

extern "C" void kernel_launch(void* const* d_in, const int* in_sizes, int n_in,
                              void* d_out, int out_size, void* d_ws, size_t ws_size,
                              hipStream_t stream) {
    const float* x      = (const float*)d_in[0];
    const float* coeffs = (const float*)d_in[1];
    const float* scale  = (const float*)d_in[2];
    const float* shift  = (const float*)d_in[3];
    float* out = (float*)d_out;

    const size_t wt_bytes   = (size_t)JDIM * KDIM * sizeof(unsigned short); // 5,898,240
    const size_t bias_off   = wt_bytes;
    const size_t bias_bytes = (size_t)JDIM * sizeof(float);
    const size_t bas_off    = bias_off + bias_bytes;
    const size_t bas_bytes  = (size_t)BATCH * KDIM * sizeof(unsigned short);
    const size_t need       = bas_off + bas_bytes;                          // ~68.8 MB

    if (ws_size >= need) {
        unsigned short* Wt   = (unsigned short*)d_ws;
        float*          bias = (float*)((char*)d_ws + bias_off);
        unsigned short* Abas = (unsigned short*)((char*)d_ws + bas_off);

        hipMemsetAsync(bias, 0, bias_bytes, stream);
        wt_bias_kernel<<<(IDIM / WT_I) * (JDIM / WT_J), 256, 0, stream>>>(coeffs, scale, shift, Wt, bias);
        basis_kernel<<<(BATCH * (IDIM / 4)) / 256, 256, 0, stream>>>(x, Abas);
        kan_gemm<<<dim3(BATCH / BM, JDIM / BN), 256, 0, stream>>>(Abas, Wt, bias, out);
    } else {
        fallback_kernel<<<BATCH, 256, 0, stream>>>(x, coeffs, scale, shift, out);
    }
}

// Round 11
// 152.841 us; speedup vs baseline: 1.0680x; 1.0290x over previous
//
#include <hip/hip_runtime.h>
#include <hip/hip_bf16.h>
#include <cstdint>
#include <cstddef>

#define BATCH 8192
#define IDIM  768
#define JDIM  768
#define GRID  5
#define KDIM  (IDIM * GRID)   // 3840

// ---------------- helpers ----------------

__device__ __forceinline__ unsigned short f2bf(float f) {
    unsigned int u = __float_as_uint(f);
    u += 0x7fffu + ((u >> 16) & 1u);
    return (unsigned short)(u >> 16);
}

typedef __bf16 bf16x8 __attribute__((ext_vector_type(8)));
typedef float  f32x4  __attribute__((ext_vector_type(4)));
typedef unsigned short ushortx4 __attribute__((ext_vector_type(4)));

__device__ __forceinline__ void async_copy16(const void* gsrc, void* ldsdst) {
    __builtin_amdgcn_global_load_lds(
        (const __attribute__((address_space(1))) unsigned int*)gsrc,
        (__attribute__((address_space(3))) unsigned int*)ldsdst,
        16, 0, 0);
}

// ---------------- precompute: Wt3 (fragment-packed) + bias ----------------
// r9: B is repacked FRAGMENT-MAJOR so the GEMM loads B frags global->VGPR
// fully coalesced, bypassing LDS (r8 PMC showed LDS BW is the GEMM floor:
// B was 59% of LDS traffic).
// Layout: Wt3[ks(120)][jf(48)][lane(64)][8]  where element =
//   coeffs[i][j][g]*scale[i][j],  j = jf*16 + (lane&15),
//   k = ks*32 + (lane>>4)*8 + e,  k = g*768 + i.
// A wave's B-frag (ks, jf) = 64 lanes x 16 B contiguous = 1 KB.

#define WT_I 32
#define WT_J 64
#define NJF  (JDIM / 16)      // 48
#define NKS  (KDIM / 32)      // 120

__global__ __launch_bounds__(256)
void wt_bias_kernel(const float* __restrict__ coeffs,
                    const float* __restrict__ scale,
                    const float* __restrict__ shift,
                    unsigned short* __restrict__ Wt3,
                    float* __restrict__ bias) {
    __shared__ __align__(16) unsigned short tile[GRID][WT_J][WT_I + 4]; // pad->36
    __shared__ float red[4][WT_J];
    const int t  = threadIdx.x;
    const int i0 = (blockIdx.x / (JDIM / WT_J)) * WT_I;
    const int j0 = (blockIdx.x % (JDIM / WT_J)) * WT_J;
    const int jj = t & 63;

    float ssum = 0.f;
#pragma unroll
    for (int it = 0; it < (WT_I * WT_J) / 256; ++it) {          // 8 iters
        const int ii = it * 4 + (t >> 6);
        const int i = i0 + ii, j = j0 + jj;
        const float* cp = &coeffs[((size_t)i * JDIM + j) * GRID];
        const float  sc = scale[(size_t)i * JDIM + j];
        ssum += shift[(size_t)i * JDIM + j];
#pragma unroll
        for (int g = 0; g < GRID; ++g)
            tile[g][jj][ii] = f2bf(cp[g] * sc);
    }
    red[t >> 6][jj] = ssum;
    __syncthreads();
    if (t < WT_J)
        atomicAdd(&bias[j0 + t], red[0][t] + red[1][t] + red[2][t] + red[3][t]);

    // write out fragment-packed: 2560 ushort4 slots / 256 threads = 10 iters
    // slot s: h=s&1 (elem half), lane=(s>>1)&63, q=s>>7: jf_l=q&3, g=q>>2
#pragma unroll
    for (int it = 0; it < 10; ++it) {
        const int s    = it * 256 + t;
        const int h    = s & 1;
        const int lane = (s >> 1) & 63;
        const int q    = s >> 7;
        const int jf_l = q & 3;
        const int g    = q >> 2;
        const int i_loc = (lane >> 4) * 8 + h * 4;
        const int j_loc = jf_l * 16 + (lane & 15);
        ushortx4 v = *(const ushortx4*)&tile[g][j_loc][i_loc];
        const int ks  = g * (IDIM / 32) + (i0 >> 5);
        const int jfg = (j0 >> 4) + jf_l;
        *(ushortx4*)&Wt3[((((size_t)ks * NJF + jfg) * 64 + lane) * 8) + h * 4] = v;
    }
}

// ---------------- precompute: basis (unchanged) ----------------

__global__ __launch_bounds__(256)
void basis_kernel(const float* __restrict__ x, unsigned short* __restrict__ Abas) {
    const int idx = blockIdx.x * 256 + threadIdx.x;
    const int b  = idx / (IDIM / 4);
    const int i4 = (idx - b * (IDIM / 4)) * 4;
    const float4 xv = *(const float4*)&x[(size_t)b * IDIM + i4];
    const float xs[4] = {xv.x, xv.y, xv.z, xv.w};
    float tv[4];
#pragma unroll
    for (int u = 0; u < 4; ++u) {
        const float e = __expf(2.f * xs[u]);
        tv[u] = 1.f - 2.f / (e + 1.f);
    }
#pragma unroll
    for (int g = 0; g < GRID; ++g) {
        const float gv = -1.f + 0.5f * (float)g;
        ushortx4 o;
#pragma unroll
        for (int u = 0; u < 4; ++u) {
            const float d = tv[u] - gv;
            o[u] = f2bf(__expf(-5.f * d * d));
        }
        *(ushortx4*)&Abas[(size_t)b * KDIM + g * IDIM + i4] = o;
    }
}

// ---------------- MFMA GEMM ----------------
// C[8192,768] = Abas @ W^T + bias.  BM=128, BN=96, BK=64.
// Grid dim3(64,8): XCD = id%8 = m%8 -> A-panel L2 reuse (r3-verified).
// A: LDS, 3-deep global_load_lds pipeline, counted vmcnt (r8-verified).
// B (r9): direct global->VGPR from fragment-packed Wt3, double-buffered in
// registers, pair-unrolled loop (static reg indices).  Removes B from LDS:
// LDS/blk-iter 170->96 KB (r8 PMC: LDS BW was the floor at MfmaUtil 30%).
// Steady vmcnt(10) = A(tt+2)[4] + B(tt+1)[6] newest in flight.

#define BM 128
#define BN 96
#define BK 64
#define KT (KDIM / BK)   // 60

__global__ __launch_bounds__(256, 2)
void kan_gemm(const unsigned short* __restrict__ Abas,  // [BATCH][KDIM]
              const unsigned short* __restrict__ Wt3,   // packed [ks][jf][lane][8]
              const float* __restrict__ bias,           // [JDIM]
              float* __restrict__ out) {                // [BATCH][JDIM]
    __shared__ unsigned short As[3][BM * BK];  // 3 x 16 KB (A only now)

    const int t    = threadIdx.x;
    const int lane = t & 63;
    const int wave = t >> 6;
    const int m0 = blockIdx.x * BM;            // grid transposed: x = M-panel
    const int n0 = blockIdx.y * BN;
    const int wm = (wave >> 1) * 64;   // 0 / 64
    const int wn = (wave & 1) * 48;    // 0 / 48

    f32x4 acc[4][3] = {};

    // A staging: thread t owns LDS slot (row=t>>3, chunk=t&7) = bytes t*16.
    // source chunk XOR-swizzled: LDS[r][c] holds global chunk c^(r&7).
    const int lrow = t >> 3;
    const int lc   = t & 7;
    const int cg   = lc ^ (lrow & 7);
    const int ldsoff = lrow * BK + lc * 8;
    const size_t abase = (size_t)(m0 + lrow) * KDIM + cg * 8;

    auto stage_a = [&](int buf, int kt_el) {
#pragma unroll
        for (int s = 0; s < 4; ++s)
            async_copy16(&Abas[abase + (size_t)(32 * s) * KDIM + kt_el],
                         &As[buf][ldsoff + 32 * s * BK]);
    };

    // B frags: wave base jframe = (n0+wn)/16; frag (ks2,f) at
    // elem offset ((ks*NJF + jfw+f)*64 + lane)*8, ks = tt*2+ks2.
    const unsigned short* bp0 = Wt3 + (((size_t)((n0 + wn) >> 4) * 64 + lane) * 8);
    auto load_b = [&](int tt, bf16x8 (&dst)[6]) {
        const unsigned short* bp = bp0 + (size_t)(tt * 2) * (NJF * 512);
#pragma unroll
        for (int ks = 0; ks < 2; ++ks)
#pragma unroll
            for (int f = 0; f < 3; ++f)
                dst[ks * 3 + f] = *(const bf16x8*)&bp[(size_t)ks * (NJF * 512) + f * 512];
    };

    auto compute_tile = [&](int ab, const bf16x8 (&bfr)[6]) {
#pragma unroll
        for (int ks = 0; ks < 2; ++ks) {
            const int pc = ((ks * 4) + (lane >> 4)) ^ (lane & 7);
            bf16x8 af[4];
#pragma unroll
            for (int f = 0; f < 4; ++f)
                af[f] = *(const bf16x8*)&As[ab][(wm + f * 16 + (lane & 15)) * BK + pc * 8];
#pragma unroll
            for (int fm = 0; fm < 4; ++fm)
#pragma unroll
                for (int fn = 0; fn < 3; ++fn)
                    acc[fm][fn] = __builtin_amdgcn_mfma_f32_16x16x32_bf16(
                        af[fm], bfr[ks * 3 + fn], acc[fm][fn], 0, 0, 0);
        }
    };

    bf16x8 b0[6], b1[6];

    // ---- prologue: A(0),A(1) -> LDS; B(0) -> regs.  14 in flight ----
    stage_a(0, 0);
    stage_a(1, BK);
    load_b(0, b0);

    // A(t) -> buf t%3.  ac = tt%3 (compute), a2 = (tt+2)%3 (stage target).
    int ac = 0, a2 = 2;
    // ---- steady: pair-unrolled tt = 0..57 (29 pairs), vmcnt(10) ----
#pragma unroll 1
    for (int p = 0; p < (KT - 2) / 2; ++p) {
        int tt = 2 * p;
        // even: compute b0, prefetch into b1
        stage_a(a2, (tt + 2) * BK);
        load_b(tt + 1, b1);
        asm volatile("s_waitcnt vmcnt(10)" ::: "memory");
        __builtin_amdgcn_s_barrier();
        __builtin_amdgcn_sched_barrier(0);
        compute_tile(ac, b0);
        __builtin_amdgcn_s_barrier();
        ac = (ac == 2) ? 0 : ac + 1;
        a2 = (a2 == 2) ? 0 : a2 + 1;
        ++tt;
        // odd: compute b1, prefetch into b0
        stage_a(a2, (tt + 2) * BK);
        load_b(tt + 1, b0);
        asm volatile("s_waitcnt vmcnt(10)" ::: "memory");
        __builtin_amdgcn_s_barrier();
        __builtin_amdgcn_sched_barrier(0);
        compute_tile(ac, b1);
        __builtin_amdgcn_s_barrier();
        ac = (ac == 2) ? 0 : ac + 1;
        a2 = (a2 == 2) ? 0 : a2 + 1;
    }
    // ---- tt = 58 (ac==1): last B prefetch; leave B(59)[6] in flight ----
    {
        load_b(KT - 1, b1);
        asm volatile("s_waitcnt vmcnt(6)" ::: "memory");
        __builtin_amdgcn_s_barrier();
        __builtin_amdgcn_sched_barrier(0);
        compute_tile(ac, b0);          // b0 = B(58), loaded at tt=57
        __builtin_amdgcn_s_barrier();
        ac = (ac == 2) ? 0 : ac + 1;   // -> 2
    }
    // ---- tt = 59: drain ----
    {
        asm volatile("s_waitcnt vmcnt(0)" ::: "memory");
        __builtin_amdgcn_s_barrier();
        __builtin_amdgcn_sched_barrier(0);
        compute_tile(ac, b1);          // b1 = B(59)
    }

    // epilogue: D mapping col=lane&15, row=(lane>>4)*4+reg  [m89/m91]
    const int col   = lane & 15;
    const int rbase = (lane >> 4) * 4;
#pragma unroll
    for (int fm = 0; fm < 4; ++fm) {
#pragma unroll
        for (int fn = 0; fn < 3; ++fn) {
            const int j  = n0 + wn + fn * 16 + col;
            const float bj = bias[j];
#pragma unroll
            for (int r = 0; r < 4; ++r) {
                const int row = m0 + wm + fm * 16 + rbase + r;
                out[(size_t)row * JDIM + j] = acc[fm][fn][r] + bj;
            }
        }
    }
}

// ---------------- fallback (ws too small): slow but correct ----------------

__global__ __launch_bounds__(256)
void fallback_kernel(const float* __restrict__ x,
                     const float* __restrict__ coeffs,
                     const float* __restrict__ scale,
                     const float* __restrict__ shift,
                     float* __restrict__ out) {
    __shared__ float bas[KDIM];
    const int b = blockIdx.x;
    const int t = threadIdx.x;
    for (int i = t; i < IDIM; i += 256) {
        float tv = tanhf(x[(size_t)b * IDIM + i]);
#pragma unroll
        for (int g = 0; g < GRID; ++g) {
            float d = tv - (-1.0f + 0.5f * (float)g);
            bas[g * IDIM + i] = __expf(-5.0f * d * d);
        }
    }
    __syncthreads();
#pragma unroll
    for (int jj = 0; jj < 3; ++jj) {
        const int j = t + jj * 256;
        float acc = 0.f;
        for (int i = 0; i < IDIM; ++i) {
            const float sc = scale[(size_t)i * JDIM + j];
            const float* cp = &coeffs[((size_t)i * JDIM + j) * GRID];
            float s5 = 0.f;
#pragma unroll
            for (int g = 0; g < GRID; ++g) s5 += bas[g * IDIM + i] * cp[g];
            acc += s5 * sc + shift[(size_t)i * JDIM + j];
        }
        out[(size_t)b * JDIM + j] = acc;
    }
}

// ---------------- launch ----------------

extern "C" void kernel_launch(void* const* d_in, const int* in_sizes, int n_in,
                              void* d_out, int out_size, void* d_ws, size_t ws_size,
                              hipStream_t stream) {
    const float* x      = (const float*)d_in[0];
    const float* coeffs = (const float*)d_in[1];
    const float* scale  = (const float*)d_in[2];
    const float* shift  = (const float*)d_in[3];
    float* out = (float*)d_out;

    const size_t wt_bytes   = (size_t)JDIM * KDIM * sizeof(unsigned short); // 5,898,240
    const size_t bias_off   = wt_bytes;
    const size_t bias_bytes = (size_t)JDIM * sizeof(float);
    const size_t bas_off    = bias_off + bias_bytes;
    const size_t bas_bytes  = (size_t)BATCH * KDIM * sizeof(unsigned short);
    const size_t need       = bas_off + bas_bytes;                          // ~68.8 MB

    if (ws_size >= need) {
        unsigned short* Wt3  = (unsigned short*)d_ws;
        float*          bias = (float*)((char*)d_ws + bias_off);
        unsigned short* Abas = (unsigned short*)((char*)d_ws + bas_off);

        hipMemsetAsync(bias, 0, bias_bytes, stream);
        wt_bias_kernel<<<(IDIM / WT_I) * (JDIM / WT_J), 256, 0, stream>>>(coeffs, scale, shift, Wt3, bias);
        basis_kernel<<<(BATCH * (IDIM / 4)) / 256, 256, 0, stream>>>(x, Abas);
        kan_gemm<<<dim3(BATCH / BM, JDIM / BN), 256, 0, stream>>>(Abas, Wt3, bias, out);
    } else {
        fallback_kernel<<<BATCH, 256, 0, stream>>>(x, coeffs, scale, shift, out);
    }
}